// Round 7
// baseline (174.521 us; speedup 1.0000x reference)
//
#include <hip/hip_runtime.h>

typedef __bf16 bf16x8 __attribute__((ext_vector_type(8)));
typedef float f32x4 __attribute__((ext_vector_type(4)));

#define AS1 __attribute__((address_space(1)))
#define AS3 __attribute__((address_space(3)))

__device__ __forceinline__ void gload_lds16(const void* g, void* l) {
  __builtin_amdgcn_global_load_lds((const AS1 void*)g, (AS3 void*)l, 16, 0, 0);
}

#define MFMA16(a, b, c) __builtin_amdgcn_mfma_f32_16x16x32_bf16((a), (b), (c), 0, 0, 0)

// ---------------------------------------------------------------- fp32 -> bf16 (all 4 tensors, one dispatch)
__global__ __launch_bounds__(256)
void cvt_all(const float* __restrict__ sem, const float* __restrict__ wq,
             const float* __restrict__ wk, const float* __restrict__ wa,
             __bf16* __restrict__ semb, __bf16* __restrict__ wcat) {
  int i = blockIdx.x * 256 + threadIdx.x;
  if (i >= 2409472) return;
  const float* in;
  __bf16* out;
  int j;
  if (i < 1310720) { in = sem; out = semb; j = i; }
  else if (i < 1835008) { in = wq; out = wcat; j = i - 1310720; }
  else if (i < 2359296) { in = wk; out = wcat + 4194304; j = i - 1835008; }
  else { in = wa; out = wcat + 8388608; j = i - 2359296; }
  const float4* p = (const float4*)in;
  float4 a = p[2 * j], b = p[2 * j + 1];
  bf16x8 v;
  v[0] = (__bf16)a.x; v[1] = (__bf16)a.y; v[2] = (__bf16)a.z; v[3] = (__bf16)a.w;
  v[4] = (__bf16)b.x; v[5] = (__bf16)b.y; v[6] = (__bf16)b.z; v[7] = (__bf16)b.w;
  *(bf16x8*)(out + (size_t)j * 8) = v;
}

// ---------------------------------------------------------------- fused projection GEMM, 256x128 tiles, 3-slot ring
// C[5120,4352] = semb[5120,2048] @ Wcat[4292,2048]^T (B rows clamped past 4291).
// cols [0,2048)->Qb bf16 +qb; [2048,4096)->Kb bf16 +kb; [4096,4292)->adj sigmoid.
// 512 thr = 8 waves (2M x 4N), wave tile 128x32. BK=64, 32 iters.
// LDS 144 KiB = 3 ring slots x (A 32K + B 16K): iter j computes slot j%3, stages tile j+2
// into slot (j+2)%3 (dead since iter j-1). End-of-iter vmcnt(6) forces tile j+1 (staged a
// FULL iter ago -> HBM latency covered); tile j+2's 6 loads stay in flight across barriers.
__global__ __launch_bounds__(512, 1)
void gemm_fused(const __bf16* __restrict__ A, const __bf16* __restrict__ B,
                const float* __restrict__ qbias, const float* __restrict__ kbias,
                const float* __restrict__ abias, __bf16* __restrict__ Qo,
                __bf16* __restrict__ Ko, float* __restrict__ adj) {
  __shared__ char smem[147456];
  char* smc = smem;
  // bijective XCD swizzle (nwg=680=8x85 exact) + 8-wide tn-band, tm-major in band
  const int bid = blockIdx.x;
  const int wgid = (bid & 7) * 85 + (bid >> 3);
  int tm, tn;
  if (wgid < 640) {
    const int band = wgid / 160, rem = wgid % 160;
    tm = rem >> 3;
    tn = band * 8 + (rem & 7);
  } else {
    const int rem = wgid - 640;
    tm = rem >> 1;
    tn = 32 + (rem & 1);
  }

  const int t = threadIdx.x;
  const int lane = t & 63;
  const int w = t >> 6, wm = w >> 2, wn = w & 3;

  // staging constants (linear LDS dest; swizzle folded into global source column)
  const int r0 = t >> 3;                       // 0..63
  const int colx = ((t & 7) ^ (r0 & 7)) * 8;   // pre-swizzled source column (elements)
  const int t16 = t * 16;
  const __bf16* Abase = A + (size_t)(tm * 256) * 2048;  // rows exact (20*256=5120)

#define SLOT(j) (smc + ((j) % 3) * 49152)
#define STAGE_TILE(kk, sl) do {                                               \
    char* dst = (sl) + t16;                                                   \
    const __bf16* ga = Abase + (size_t)r0 * 2048 + (kk) * 64 + colx;          \
    gload_lds16(ga,                       dst);                               \
    gload_lds16(ga + (size_t)64 * 2048,   dst + 8192);                        \
    gload_lds16(ga + (size_t)128 * 2048,  dst + 16384);                       \
    gload_lds16(ga + (size_t)192 * 2048,  dst + 24576);                       \
    int br0 = tn * 128 + r0;       br0 = br0 < 4292 ? br0 : 4291;             \
    int br1 = tn * 128 + 64 + r0;  br1 = br1 < 4292 ? br1 : 4291;             \
    gload_lds16(B + (size_t)br0 * 2048 + (kk) * 64 + colx, dst + 32768);      \
    gload_lds16(B + (size_t)br1 * 2048 + (kk) * 64 + colx, dst + 40960);      \
  } while (0)

  // fragment-read constants (swizzled ds_read)
  const int rbase = (lane & 15) * 128;
  const int g16 = (lane >> 4) * 16;
  const int x16 = (lane & 7) << 4;
  const int aoff = wm * 16384 + rbase;          // wm*128 rows * 128B
  const int boff = 32768 + wn * 4096 + rbase;   // wn*32 rows * 128B

#define LDA(sl, m, kh) (*(const bf16x8*)((sl) + aoff + (m) * 2048 + ((((kh) * 64) + g16) ^ x16)))
#define LDB(sl, n, kh) (*(const bf16x8*)((sl) + boff + (n) * 2048 + ((((kh) * 64) + g16) ^ x16)))

  f32x4 acc[8][2];
#pragma unroll
  for (int m = 0; m < 8; ++m)
#pragma unroll
    for (int n = 0; n < 2; ++n) acc[m][n] = (f32x4){0.f, 0.f, 0.f, 0.f};

  // prologue: tiles 0,1 into slots 0,1; force tile 0 (leave tile 1's 6 loads in flight)
  STAGE_TILE(0, SLOT(0));
  STAGE_TILE(1, SLOT(1));
  asm volatile("s_waitcnt vmcnt(6)" ::: "memory");
  __builtin_amdgcn_s_barrier();

  for (int j = 0; j < 32; ++j) {
    char* sl = SLOT(j);
    if (j < 30) STAGE_TILE(j + 2, SLOT(j + 2));
    bf16x8 a0[8], b0[2];
#pragma unroll
    for (int m = 0; m < 8; ++m) a0[m] = LDA(sl, m, 0);
#pragma unroll
    for (int n = 0; n < 2; ++n) b0[n] = LDB(sl, n, 0);
    __builtin_amdgcn_s_setprio(1);
#pragma unroll
    for (int m = 0; m < 8; ++m)
#pragma unroll
      for (int n = 0; n < 2; ++n) acc[m][n] = MFMA16(a0[m], b0[n], acc[m][n]);
    __builtin_amdgcn_s_setprio(0);
    bf16x8 a1[8], b1[2];
#pragma unroll
    for (int m = 0; m < 8; ++m) a1[m] = LDA(sl, m, 1);
#pragma unroll
    for (int n = 0; n < 2; ++n) b1[n] = LDB(sl, n, 1);
    __builtin_amdgcn_s_setprio(1);
#pragma unroll
    for (int m = 0; m < 8; ++m)
#pragma unroll
      for (int n = 0; n < 2; ++n) acc[m][n] = MFMA16(a1[m], b1[n], acc[m][n]);
    __builtin_amdgcn_s_setprio(0);
    // counted wait: force tile j+1 (staged at iter j-1); leave tile j+2's 6 loads in flight
    if (j < 30) asm volatile("s_waitcnt vmcnt(6)" ::: "memory");
    else if (j == 30) asm volatile("s_waitcnt vmcnt(0)" ::: "memory");
    __builtin_amdgcn_s_barrier();
  }

  // ---- epilogue
  if (tn < 32) {
    // bias-add + bf16 into LDS [256][136], then coalesced 16B row-major stores
    __bf16* so = (__bf16*)smc;
    const float* bias = (tn < 16) ? (qbias + tn * 128) : (kbias + (tn - 16) * 128);
#pragma unroll
    for (int n = 0; n < 2; ++n) {
      const int colb = wn * 32 + n * 16 + (lane & 15);
      const float bv = bias[colb];
#pragma unroll
      for (int m = 0; m < 8; ++m) {
        const int rw = wm * 128 + m * 16 + (lane >> 4) * 4;
#pragma unroll
        for (int jj = 0; jj < 4; ++jj)
          so[(rw + jj) * 136 + colb] = (__bf16)(acc[m][n][jj] + bv);
      }
    }
    __syncthreads();
    __bf16* dst = (tn < 16) ? (Qo + tn * 128) : (Ko + (tn - 16) * 128);
    for (int idx = t; idx < 4096; idx += 512) {  // 256 rows x 16 16B-chunks
      const int row = idx >> 4, c = idx & 15;
      const int grow = tm * 256 + row;  // always < 5120
      bf16x8 v = *(const bf16x8*)(so + row * 136 + c * 8);
      *(bf16x8*)(dst + (size_t)grow * 2048 + c * 8) = v;
    }
  } else {
    // adj region (cols 4096..4291): scattered f32 sigmoid stores (small)
#pragma unroll
    for (int n = 0; n < 2; ++n) {
      const int colg = (tn - 32) * 128 + wn * 32 + n * 16 + (lane & 15);
      if (colg < 196) {
        const float bv = abias[colg];
#pragma unroll
        for (int m = 0; m < 8; ++m)
#pragma unroll
          for (int jj = 0; jj < 4; ++jj) {
            const int row = tm * 256 + wm * 128 + m * 16 + (lane >> 4) * 4 + jj;
            const float v = acc[m][n][jj] + bv;
            adj[(size_t)row * 196 + colg] = 1.f / (1.f + __expf(-v));
          }
      }
    }
  }
#undef SLOT
#undef STAGE_TILE
#undef LDA
#undef LDB
}

// ---------------------------------------------------------------- attention 1/3: partial S
// grid (64 b x 8 kq): S_part[b][kq] = Q_b[:, kq*256..+256] @ K_b[...]^T  (f32 80x80)
__global__ __launch_bounds__(256)
void attn_s(const __bf16* __restrict__ Qb, const __bf16* __restrict__ Kb,
            float* __restrict__ Spart) {
  __shared__ char smem[81920];
  __bf16* sQ = (__bf16*)smem;            // [80][256]
  __bf16* sK = (__bf16*)(smem + 40960);  // [80][256]
  const int b = blockIdx.x >> 3, kq = blockIdx.x & 7;
  const int kc = kq * 256;
  const int t = threadIdx.x, lane = t & 63, w = t >> 6;
  const __bf16* Qbase = Qb + (size_t)b * 163840;
  const __bf16* Kbase = Kb + (size_t)b * 163840;

#pragma unroll
  for (int s = 0; s < 10; ++s) {
    const int i = t + s * 256;
    const int row = i >> 5, cb = i & 31;
    gload_lds16(Qbase + (size_t)row * 2048 + kc + cb * 8, sQ + i * 8);
  }
#pragma unroll
  for (int s = 0; s < 10; ++s) {
    const int i = t + s * 256;
    const int row = i >> 5, cb = i & 31;
    gload_lds16(Kbase + (size_t)row * 2048 + kc + cb * 8, sK + i * 8);
  }
  __syncthreads();

  f32x4 acc[7];
#pragma unroll
  for (int u = 0; u < 7; ++u) acc[u] = (f32x4){0.f, 0.f, 0.f, 0.f};
#pragma unroll
  for (int u = 0; u < 7; ++u) {
    const int tl = w + u * 4;
    if (tl < 25) {
      const int qi = tl / 5, kj = tl % 5;
#pragma unroll
      for (int k0 = 0; k0 < 256; k0 += 32) {
        bf16x8 a = *(const bf16x8*)(sQ + (qi * 16 + (lane & 15)) * 256 + k0 + (lane >> 4) * 8);
        bf16x8 kk = *(const bf16x8*)(sK + (kj * 16 + (lane & 15)) * 256 + k0 + (lane >> 4) * 8);
        acc[u] = MFMA16(a, kk, acc[u]);
      }
    }
  }
  float* Sp = Spart + (size_t)(b * 8 + kq) * 6400;
#pragma unroll
  for (int u = 0; u < 7; ++u) {
    const int tl = w + u * 4;
    if (tl < 25) {
      const int qi = tl / 5, kj = tl % 5;
#pragma unroll
      for (int jj = 0; jj < 4; ++jj) {
        const int r = qi * 16 + (lane >> 4) * 4 + jj;
        const int c = kj * 16 + (lane & 15);
        Sp[r * 80 + c] = acc[u][jj];
      }
    }
  }
}

// ---------------------------------------------------------------- attention 2/3: softmax
// grid 64: sum 8 partials, softmax(S*scale*mask), write P bf16 [80][96] (zero-padded)
__global__ __launch_bounds__(256)
void attn_soft(const float* __restrict__ Spart, const float* __restrict__ mask,
               __bf16* __restrict__ Pg) {
  __shared__ float S[80 * 81];
  const int b = blockIdx.x, t = threadIdx.x;
  const float* Sp = Spart + (size_t)b * 8 * 6400;
  for (int idx = t; idx < 6400; idx += 256) {
    float s = 0.f;
#pragma unroll
    for (int p = 0; p < 8; ++p) s += Sp[p * 6400 + idx];
    const int r = idx / 80, c = idx - r * 80;
    S[r * 81 + c] = s;
  }
  __syncthreads();
  if (t < 80) {
    const float scale = 0.02209708691207961f;  // 1/sqrt(2048)
    float mx = -1e30f;
    for (int k = 0; k < 80; ++k) {
      float v = S[t * 81 + k] * scale * mask[t * 80 + k];
      S[t * 81 + k] = v;
      mx = fmaxf(mx, v);
    }
    float sum = 0.f;
    for (int k = 0; k < 80; ++k) {
      float e = __expf(S[t * 81 + k] - mx);
      S[t * 81 + k] = e;
      sum += e;
    }
    const float r = 1.f / sum;
    __bf16* Pr = Pg + (size_t)b * 7680 + t * 96;
    for (int k = 0; k < 80; ++k) Pr[k] = (__bf16)(S[t * 81 + k] * r);
    for (int k = 80; k < 96; ++k) Pr[k] = (__bf16)0.f;
  }
}

// ---------------------------------------------------------------- attention 3/3: PV + epilogue
__global__ __launch_bounds__(256)
void attn_pv(const __bf16* __restrict__ Pg, const float* __restrict__ feats,
             const float* __restrict__ adj, float* __restrict__ out) {
  __shared__ __bf16 Ft[64 * 104];
  const int b = blockIdx.x >> 2, hq = blockIdx.x & 3;
  const int hb = hq * 49;
  const int t = threadIdx.x, lane = t & 63, w = t >> 6;
  for (int idx = t; idx < 4704; idx += 256) {  // 96*49
    const int k = idx / 49, h = idx - k * 49;
    Ft[h * 104 + k] = (k < 80) ? (__bf16)feats[(size_t)b * 15680 + k * 196 + hb + h]
                               : (__bf16)0.f;
  }
  __syncthreads();
  const __bf16* Pb = Pg + (size_t)b * 7680;
#pragma unroll
  for (int u = 0; u < 5; ++u) {
    const int tl = w + u * 4;  // 0..19
    const int ci = tl >> 2, hj = tl & 3;
    f32x4 a2 = (f32x4){0.f, 0.f, 0.f, 0.f};
#pragma unroll
    for (int k0 = 0; k0 < 96; k0 += 32) {
      bf16x8 pa = *(const bf16x8*)(Pb + (ci * 16 + (lane & 15)) * 96 + k0 + (lane >> 4) * 8);
      bf16x8 fb = *(const bf16x8*)(Ft + (hj * 16 + (lane & 15)) * 104 + k0 + (lane >> 4) * 8);
      a2 = MFMA16(pa, fb, a2);
    }
#pragma unroll
    for (int jj = 0; jj < 4; ++jj) {
      const int c = ci * 16 + (lane >> 4) * 4 + jj;
      const int h2 = hj * 16 + (lane & 15);
      if (h2 < 49) {
        const size_t o = (size_t)b * 15680 + (size_t)c * 196 + hb + h2;
        out[o] = (feats[o] + a2[jj]) * adj[o];
      }
    }
  }
}

// ---------------------------------------------------------------- launch
extern "C" void kernel_launch(void* const* d_in, const int* in_sizes, int n_in,
                              void* d_out, int out_size, void* d_ws, size_t ws_size,
                              hipStream_t stream) {
  const float* features = (const float*)d_in[0];
  const float* sem      = (const float*)d_in[1];
  const float* mask     = (const float*)d_in[2];
  const float* Wq_w     = (const float*)d_in[3];
  const float* Wq_b     = (const float*)d_in[4];
  const float* Wk_w     = (const float*)d_in[5];
  const float* Wk_b     = (const float*)d_in[6];
  const float* Wa_w     = (const float*)d_in[7];
  const float* Wa_b     = (const float*)d_in[8];
  float* out = (float*)d_out;

  char* ws = (char*)d_ws;
  __bf16* semb = (__bf16*)ws;                   // 5120x2048 bf16
  __bf16* wcat = (__bf16*)(ws + 20971520);      // 4292x2048 bf16
  __bf16* Qb   = (__bf16*)(ws + 38551552);
  __bf16* Kb   = (__bf16*)(ws + 59523072);
  float*  adj  = (float*)(ws + 80494592);       // 5120x196 f32 (total 84.5 MB)
  float*  Spart = (float*)ws;                   // 64*8*6400 f32 = 13.1 MB (aliases semb, dead after gemm)
  __bf16* Pg    = (__bf16*)(ws + 20971520);     // aliases wcat (dead after gemm)

  cvt_all<<<9412, 256, 0, stream>>>(sem, Wq_w, Wk_w, Wa_w, semb, wcat);
  gemm_fused<<<680, 512, 0, stream>>>(semb, wcat, Wq_b, Wk_b, Wa_b, Qb, Kb, adj);
  attn_s<<<512, 256, 0, stream>>>(Qb, Kb, Spart);
  attn_soft<<<64, 256, 0, stream>>>(Spart, mask, Pg);
  attn_pv<<<256, 256, 0, stream>>>(Pg, features, adj, out);
}

// Round 8
// 173.822 us; speedup vs baseline: 1.0040x; 1.0040x over previous
//
#include <hip/hip_runtime.h>

typedef __bf16 bf16x8 __attribute__((ext_vector_type(8)));
typedef float f32x4 __attribute__((ext_vector_type(4)));

#define AS1 __attribute__((address_space(1)))
#define AS3 __attribute__((address_space(3)))

__device__ __forceinline__ void gload_lds16(const void* g, void* l) {
  __builtin_amdgcn_global_load_lds((const AS1 void*)g, (AS3 void*)l, 16, 0, 0);
}

#define MFMA16(a, b, c) __builtin_amdgcn_mfma_f32_16x16x32_bf16((a), (b), (c), 0, 0, 0)

// ---------------------------------------------------------------- fp32 -> bf16 (all 4 tensors, one dispatch)
__global__ __launch_bounds__(256)
void cvt_all(const float* __restrict__ sem, const float* __restrict__ wq,
             const float* __restrict__ wk, const float* __restrict__ wa,
             __bf16* __restrict__ semb, __bf16* __restrict__ wcat) {
  int i = blockIdx.x * 256 + threadIdx.x;
  if (i >= 2409472) return;
  const float* in;
  __bf16* out;
  int j;
  if (i < 1310720) { in = sem; out = semb; j = i; }
  else if (i < 1835008) { in = wq; out = wcat; j = i - 1310720; }
  else if (i < 2359296) { in = wk; out = wcat + 4194304; j = i - 1835008; }
  else { in = wa; out = wcat + 8388608; j = i - 2359296; }
  const float4* p = (const float4*)in;
  float4 a = p[2 * j], b = p[2 * j + 1];
  bf16x8 v;
  v[0] = (__bf16)a.x; v[1] = (__bf16)a.y; v[2] = (__bf16)a.z; v[3] = (__bf16)a.w;
  v[4] = (__bf16)b.x; v[5] = (__bf16)b.y; v[6] = (__bf16)b.z; v[7] = (__bf16)b.w;
  *(bf16x8*)(out + (size_t)j * 8) = v;
}

// ---------------------------------------------------------------- fused projection GEMM
// C[5184(pad),4352] = semb[5120,2048] @ Wcat[4292,2048]^T (rows clamped).
// cols [0,2048)->Qb bf16 +qb; [2048,4096)->Kb bf16 +kb; [4096,4292)->adj sigmoid.
// 256 thr = 4 waves (2M x 2N), wave tile 96x64 -> LDS reads/MFMA at parity with
// the matrix pipe (the r6/r7 cap was LDS-read BW from small wave tiles).
// BK=32, 64 iters, ring-of-4 slots (4 x 20 KiB = 80 KiB -> 2 blocks/CU).
// Per iter j: stage tile j+2 into slot (j+2)%4 (dead 2 iters); end-of-iter
// vmcnt(5) forces tile j+1 (issued a full iter ago -> latency covered), leaves
// tile j+2's 5 loads in flight. Linear LDS (BK=32 reads are bank-self-balanced).
__global__ __launch_bounds__(256, 2)
void gemm_fused(const __bf16* __restrict__ A, const __bf16* __restrict__ B,
                const float* __restrict__ qbias, const float* __restrict__ kbias,
                const float* __restrict__ abias, __bf16* __restrict__ Qo,
                __bf16* __restrict__ Ko, float* __restrict__ adj) {
  __shared__ char smem[81920];
  char* smc = smem;
  // bijective XCD chunking (nwg=918, q=114, r=6) + 8-wide tn-band, tm-major in band
  const int bid = blockIdx.x;
  const int xcd = bid & 7, sidx = bid >> 3;
  const int wgid = (xcd < 6 ? xcd * 115 : 690 + (xcd - 6) * 114) + sidx;
  int tm, tn;
  if (wgid < 864) {
    const int band = wgid / 216, rem = wgid % 216;
    tm = rem >> 3;
    tn = band * 8 + (rem & 7);
  } else {
    const int rem = wgid - 864;
    tm = rem >> 1;
    tn = 32 + (rem & 1);
  }

  const int t = threadIdx.x;
  const int lane = t & 63;
  const int w = t >> 6, wm = w >> 1, wn = w & 1;

  // ---- staging precompute: 20 wave-ops per tile (A rows: ops 0-11, B rows: 12-19);
  // wave w does ops 5w..5w+4; each op = 64 lanes x 16B = 16 rows x 64B (one BK=32 stripe).
  const __bf16* gsrc[5];
  int ldst[5];
#pragma unroll
  for (int i = 0; i < 5; ++i) {
    const int o = w * 5 + i;
    if (o < 12) {
      int row = tm * 192 + o * 16 + (lane >> 2);
      row = row < 5120 ? row : 5119;
      gsrc[i] = A + (size_t)row * 2048 + (lane & 3) * 8;
    } else {
      int row = tn * 128 + (o - 12) * 16 + (lane >> 2);
      row = row < 4292 ? row : 4291;
      gsrc[i] = B + (size_t)row * 2048 + (lane & 3) * 8;
    }
    ldst[i] = o * 1024 + lane * 16;
  }

#define SLOT(j) (((j) & 3) * 20480)
#define STAGE_TILE(kk, sb) do {                                               \
    char* dst = smc + (sb);                                                   \
    _Pragma("unroll")                                                         \
    for (int i = 0; i < 5; ++i)                                               \
      gload_lds16(gsrc[i] + (size_t)(kk) * 32, dst + ldst[i]);                \
  } while (0)

  // ---- fragment reads (linear): A at slot+row*64+(lane>>4)*16; B at slot+12288+...
  const int arb = (wm * 96 + (lane & 15)) * 64 + (lane >> 4) * 16;
  const int brb = 12288 + (wn * 64 + (lane & 15)) * 64 + (lane >> 4) * 16;

  f32x4 acc[6][4];
#pragma unroll
  for (int m = 0; m < 6; ++m)
#pragma unroll
    for (int n = 0; n < 4; ++n) acc[m][n] = (f32x4){0.f, 0.f, 0.f, 0.f};

  // prologue: tiles 0,1 -> slots 0,1; force tile 0 (leave tile 1's 5 in flight)
  STAGE_TILE(0, SLOT(0));
  STAGE_TILE(1, SLOT(1));
  asm volatile("s_waitcnt vmcnt(5)" ::: "memory");
  __builtin_amdgcn_s_barrier();

  for (int j = 0; j < 64; ++j) {
    const int sb = SLOT(j);
    if (j < 62) STAGE_TILE(j + 2, SLOT(j + 2));
    bf16x8 af[6], bf[4];
#pragma unroll
    for (int m = 0; m < 6; ++m) af[m] = *(const bf16x8*)(smc + sb + arb + m * 1024);
#pragma unroll
    for (int n = 0; n < 4; ++n) bf[n] = *(const bf16x8*)(smc + sb + brb + n * 1024);
    __builtin_amdgcn_s_setprio(1);
#pragma unroll
    for (int m = 0; m < 6; ++m)
#pragma unroll
      for (int n = 0; n < 4; ++n) acc[m][n] = MFMA16(af[m], bf[n], acc[m][n]);
    __builtin_amdgcn_s_setprio(0);
    // counted wait: force tile j+1 landed; leave tile j+2's 5 loads in flight
    if (j < 62) asm volatile("s_waitcnt vmcnt(5)" ::: "memory");
    else if (j == 62) asm volatile("s_waitcnt vmcnt(0)" ::: "memory");
    __builtin_amdgcn_s_barrier();
  }

  // ---- epilogue
  if (tn < 32) {
    // bias-add + bf16 into LDS [192][136], then coalesced 16B row-major stores
    __bf16* so = (__bf16*)smc;
    const float* bias = (tn < 16) ? (qbias + tn * 128) : (kbias + (tn - 16) * 128);
#pragma unroll
    for (int n = 0; n < 4; ++n) {
      const int colb = wn * 64 + n * 16 + (lane & 15);
      const float bv = bias[colb];
#pragma unroll
      for (int m = 0; m < 6; ++m) {
        const int rw = wm * 96 + m * 16 + (lane >> 4) * 4;
#pragma unroll
        for (int jj = 0; jj < 4; ++jj)
          so[(rw + jj) * 136 + colb] = (__bf16)(acc[m][n][jj] + bv);
      }
    }
    __syncthreads();
    __bf16* dst = (tn < 16) ? (Qo + tn * 128) : (Ko + (tn - 16) * 128);
    for (int idx = t; idx < 3072; idx += 256) {  // 192 rows x 16 16B-chunks
      const int row = idx >> 4, c = idx & 15;
      const int grow = tm * 192 + row;
      if (grow < 5120) {
        bf16x8 v = *(const bf16x8*)(so + row * 136 + c * 8);
        *(bf16x8*)(dst + (size_t)grow * 2048 + c * 8) = v;
      }
    }
  } else {
    // adj region (cols 4096..4291): scattered f32 sigmoid stores (small)
#pragma unroll
    for (int n = 0; n < 4; ++n) {
      const int colg = (tn - 32) * 128 + wn * 64 + n * 16 + (lane & 15);
      if (colg < 196) {
        const float bv = abias[colg];
#pragma unroll
        for (int m = 0; m < 6; ++m)
#pragma unroll
          for (int jj = 0; jj < 4; ++jj) {
            const int row = tm * 192 + wm * 96 + m * 16 + (lane >> 4) * 4 + jj;
            if (row < 5120) {
              const float v = acc[m][n][jj] + bv;
              adj[(size_t)row * 196 + colg] = 1.f / (1.f + __expf(-v));
            }
          }
      }
    }
  }
#undef SLOT
#undef STAGE_TILE
}

// ---------------------------------------------------------------- attention 1/3: partial S
// grid (64 b x 8 kq): S_part[b][kq] = Q_b[:, kq*256..+256] @ K_b[...]^T  (f32 80x80)
__global__ __launch_bounds__(256)
void attn_s(const __bf16* __restrict__ Qb, const __bf16* __restrict__ Kb,
            float* __restrict__ Spart) {
  __shared__ char smem[81920];
  __bf16* sQ = (__bf16*)smem;            // [80][256]
  __bf16* sK = (__bf16*)(smem + 40960);  // [80][256]
  const int b = blockIdx.x >> 3, kq = blockIdx.x & 7;
  const int kc = kq * 256;
  const int t = threadIdx.x, lane = t & 63, w = t >> 6;
  const __bf16* Qbase = Qb + (size_t)b * 163840;
  const __bf16* Kbase = Kb + (size_t)b * 163840;

#pragma unroll
  for (int s = 0; s < 10; ++s) {
    const int i = t + s * 256;
    const int row = i >> 5, cb = i & 31;
    gload_lds16(Qbase + (size_t)row * 2048 + kc + cb * 8, sQ + i * 8);
  }
#pragma unroll
  for (int s = 0; s < 10; ++s) {
    const int i = t + s * 256;
    const int row = i >> 5, cb = i & 31;
    gload_lds16(Kbase + (size_t)row * 2048 + kc + cb * 8, sK + i * 8);
  }
  __syncthreads();

  f32x4 acc[7];
#pragma unroll
  for (int u = 0; u < 7; ++u) acc[u] = (f32x4){0.f, 0.f, 0.f, 0.f};
#pragma unroll
  for (int u = 0; u < 7; ++u) {
    const int tl = w + u * 4;
    if (tl < 25) {
      const int qi = tl / 5, kj = tl % 5;
#pragma unroll
      for (int k0 = 0; k0 < 256; k0 += 32) {
        bf16x8 a = *(const bf16x8*)(sQ + (qi * 16 + (lane & 15)) * 256 + k0 + (lane >> 4) * 8);
        bf16x8 kk = *(const bf16x8*)(sK + (kj * 16 + (lane & 15)) * 256 + k0 + (lane >> 4) * 8);
        acc[u] = MFMA16(a, kk, acc[u]);
      }
    }
  }
  float* Sp = Spart + (size_t)(b * 8 + kq) * 6400;
#pragma unroll
  for (int u = 0; u < 7; ++u) {
    const int tl = w + u * 4;
    if (tl < 25) {
      const int qi = tl / 5, kj = tl % 5;
#pragma unroll
      for (int jj = 0; jj < 4; ++jj) {
        const int r = qi * 16 + (lane >> 4) * 4 + jj;
        const int c = kj * 16 + (lane & 15);
        Sp[r * 80 + c] = acc[u][jj];
      }
    }
  }
}

// ---------------------------------------------------------------- attention 2/3: softmax
__global__ __launch_bounds__(256)
void attn_soft(const float* __restrict__ Spart, const float* __restrict__ mask,
               __bf16* __restrict__ Pg) {
  __shared__ float S[80 * 81];
  const int b = blockIdx.x, t = threadIdx.x;
  const float* Sp = Spart + (size_t)b * 8 * 6400;
  for (int idx = t; idx < 6400; idx += 256) {
    float s = 0.f;
#pragma unroll
    for (int p = 0; p < 8; ++p) s += Sp[p * 6400 + idx];
    const int r = idx / 80, c = idx - r * 80;
    S[r * 81 + c] = s;
  }
  __syncthreads();
  if (t < 80) {
    const float scale = 0.02209708691207961f;  // 1/sqrt(2048)
    float mx = -1e30f;
    for (int k = 0; k < 80; ++k) {
      float v = S[t * 81 + k] * scale * mask[t * 80 + k];
      S[t * 81 + k] = v;
      mx = fmaxf(mx, v);
    }
    float sum = 0.f;
    for (int k = 0; k < 80; ++k) {
      float e = __expf(S[t * 81 + k] - mx);
      S[t * 81 + k] = e;
      sum += e;
    }
    const float r = 1.f / sum;
    __bf16* Pr = Pg + (size_t)b * 7680 + t * 96;
    for (int k = 0; k < 80; ++k) Pr[k] = (__bf16)(S[t * 81 + k] * r);
    for (int k = 80; k < 96; ++k) Pr[k] = (__bf16)0.f;
  }
}

// ---------------------------------------------------------------- attention 3/3: PV + epilogue
__global__ __launch_bounds__(256)
void attn_pv(const __bf16* __restrict__ Pg, const float* __restrict__ feats,
             const float* __restrict__ adj, float* __restrict__ out) {
  __shared__ __bf16 Ft[64 * 104];
  const int b = blockIdx.x >> 2, hq = blockIdx.x & 3;
  const int hb = hq * 49;
  const int t = threadIdx.x, lane = t & 63, w = t >> 6;
  for (int idx = t; idx < 4704; idx += 256) {  // 96*49
    const int k = idx / 49, h = idx - k * 49;
    Ft[h * 104 + k] = (k < 80) ? (__bf16)feats[(size_t)b * 15680 + k * 196 + hb + h]
                               : (__bf16)0.f;
  }
  __syncthreads();
  const __bf16* Pb = Pg + (size_t)b * 7680;
#pragma unroll
  for (int u = 0; u < 5; ++u) {
    const int tl = w + u * 4;  // 0..19
    const int ci = tl >> 2, hj = tl & 3;
    f32x4 a2 = (f32x4){0.f, 0.f, 0.f, 0.f};
#pragma unroll
    for (int k0 = 0; k0 < 96; k0 += 32) {
      bf16x8 pa = *(const bf16x8*)(Pb + (ci * 16 + (lane & 15)) * 96 + k0 + (lane >> 4) * 8);
      bf16x8 fb = *(const bf16x8*)(Ft + (hj * 16 + (lane & 15)) * 104 + k0 + (lane >> 4) * 8);
      a2 = MFMA16(pa, fb, a2);
    }
#pragma unroll
    for (int jj = 0; jj < 4; ++jj) {
      const int c = ci * 16 + (lane >> 4) * 4 + jj;
      const int h2 = hj * 16 + (lane & 15);
      if (h2 < 49) {
        const size_t o = (size_t)b * 15680 + (size_t)c * 196 + hb + h2;
        out[o] = (feats[o] + a2[jj]) * adj[o];
      }
    }
  }
}

// ---------------------------------------------------------------- launch
extern "C" void kernel_launch(void* const* d_in, const int* in_sizes, int n_in,
                              void* d_out, int out_size, void* d_ws, size_t ws_size,
                              hipStream_t stream) {
  const float* features = (const float*)d_in[0];
  const float* sem      = (const float*)d_in[1];
  const float* mask     = (const float*)d_in[2];
  const float* Wq_w     = (const float*)d_in[3];
  const float* Wq_b     = (const float*)d_in[4];
  const float* Wk_w     = (const float*)d_in[5];
  const float* Wk_b     = (const float*)d_in[6];
  const float* Wa_w     = (const float*)d_in[7];
  const float* Wa_b     = (const float*)d_in[8];
  float* out = (float*)d_out;

  char* ws = (char*)d_ws;
  __bf16* semb = (__bf16*)ws;                   // 5120x2048 bf16
  __bf16* wcat = (__bf16*)(ws + 20971520);      // 4292x2048 bf16
  __bf16* Qb   = (__bf16*)(ws + 38551552);
  __bf16* Kb   = (__bf16*)(ws + 59523072);
  float*  adj  = (float*)(ws + 80494592);       // 5120x196 f32 (total 84.5 MB)
  float*  Spart = (float*)ws;                   // 64*8*6400 f32 = 13.1 MB (aliases semb)
  __bf16* Pg    = (__bf16*)(ws + 20971520);     // aliases wcat (dead after gemm)

  cvt_all<<<9412, 256, 0, stream>>>(sem, Wq_w, Wk_w, Wa_w, semb, wcat);
  gemm_fused<<<918, 256, 0, stream>>>(semb, wcat, Wq_b, Wk_b, Wa_b, Qb, Kb, adj);
  attn_s<<<512, 256, 0, stream>>>(Qb, Kb, Spart);
  attn_soft<<<64, 256, 0, stream>>>(Spart, mask, Pg);
  attn_pv<<<256, 256, 0, stream>>>(Pg, features, adj, out);
}